// Round 22
// baseline (147.581 us; speedup 1.0000x reference)
//
#include <hip/hip_runtime.h>
#include <hip/hip_bf16.h>
#include <cstdint>
#include <cstddef>

#define B_ 4
#define T_ 2048
#define E_ 1024
#define H_ 8
#define D_ 128

typedef unsigned short u16;
typedef __bf16 bf16x8 __attribute__((ext_vector_type(8)));
typedef float f32x4 __attribute__((ext_vector_type(4)));

#define MFMA16(a, b, c) __builtin_amdgcn_mfma_f32_16x16x32_bf16((a), (b), (c), 0, 0, 0)

#if defined(__has_builtin)
#if __has_builtin(__builtin_amdgcn_global_load_lds)
#define HAVE_GLL 1
#endif
#if __has_builtin(__builtin_amdgcn_exp2f)
#define HAVE_EXP2 1
#endif
#endif

__device__ __forceinline__ void gload_lds16(const u16* g, u16* l) {
#ifdef HAVE_GLL
  __builtin_amdgcn_global_load_lds(
      (const __attribute__((address_space(1))) void*)g,
      (__attribute__((address_space(3))) void*)l, 16, 0, 0);
#else
  int lane = threadIdx.x & 63;
  *(uint4*)(l + lane * 8) = *(const uint4*)(g);
#endif
}

// 2^x via raw v_exp_f32
__device__ __forceinline__ float fexp2(float x) {
#ifdef HAVE_EXP2
  return __builtin_amdgcn_exp2f(x);
#else
  return __expf(x * 0.69314718056f);
#endif
}

__device__ __forceinline__ u16 f2bf(float f) {
  union { float f; uint32_t u; } a; a.f = f;
  uint32_t u = a.u;
  uint32_t r = (u + 0x7fffu + ((u >> 16) & 1u)) >> 16;  // RNE
  return (u16)r;
}

__device__ __forceinline__ uint32_t pkbf(float lo, float hi) {
  uint32_t r;
  asm volatile("v_cvt_pk_bf16_f32 %0, %1, %2" : "=v"(r) : "v"(lo), "v"(hi));
  return r;
}

__device__ __forceinline__ void cvt4(const float* __restrict__ s, u16* __restrict__ d, int i4) {
  float4 v = *(const float4*)(s + (size_t)i4 * 4);
  uint2 o;
  o.x = (uint32_t)f2bf(v.x) | ((uint32_t)f2bf(v.y) << 16);
  o.y = (uint32_t)f2bf(v.z) | ((uint32_t)f2bf(v.w) << 16);
  *(uint2*)(d + (size_t)i4 * 4) = o;
}

// ---- fused prep: all fp32->bf16 conversions + PE table, one launch ----
__global__ __launch_bounds__(256) void prep_kernel(
    const float* __restrict__ x,  const float* __restrict__ Wq,
    const float* __restrict__ Wk, const float* __restrict__ Wv,
    const float* __restrict__ Wo,
    u16* __restrict__ xbf, u16* __restrict__ Wcat, u16* __restrict__ Wobf,
    float* __restrict__ pe)
{
  int id = blockIdx.x * 256 + threadIdx.x;
  if (id < 2097152) { cvt4(x, xbf, id); return; }
  id -= 2097152;
  if (id < 262144) { cvt4(Wq, Wcat, id); return; }
  id -= 262144;
  if (id < 32768) { cvt4(Wk, Wcat + 1048576, id); return; }
  id -= 32768;
  if (id < 32768) { cvt4(Wv, Wcat + 1179648, id); return; }
  id -= 32768;
  if (id < 262144) { cvt4(Wo, Wobf, id); return; }
  id -= 262144;
  // PE: id in [0, 131072)
  int t = id >> 6, i = id & 63;
  float f = expf(-logf(10000.0f) * (float)i / 64.0f);
  float ang = (float)t * f;
  pe[t * 128 + 2 * i]     = sinf(ang);
  pe[t * 128 + 2 * i + 1] = cosf(ang);
}

// ---- NT GEMM, m97 structure, BK=32 (R21-exact) ----
template<int MODE>
__global__ __launch_bounds__(256) void gemm_nt(
    const u16* __restrict__ A, const u16* __restrict__ Bm,
    u16* __restrict__ Qb, u16* __restrict__ Kb, u16* __restrict__ VTb,
    const float* __restrict__ pe, float* __restrict__ Cout, int K)
{
  __shared__ u16 Al[128 * 32];
  __shared__ u16 Bl[128 * 32];
  const int t = threadIdx.x;
  const int l = t & 63, w = t >> 6;
  const int wr = w >> 1, wc = w & 1;
  const int bm = blockIdx.x * 128, bn = blockIdx.y * 128;
  const int lr = l & 15, lg = l >> 4;

  const int srow = w * 32 + (l >> 2);
  const int scol = (l & 3) * 8;
  const u16* gA0 = A + (size_t)(bm + srow) * K + scol;
  const u16* gB0 = Bm + (size_t)(bn + srow) * K + scol;
  u16* lA0 = &Al[(w * 32) * 32];
  u16* lA1 = &Al[(w * 32 + 16) * 32];
  u16* lB0 = &Bl[(w * 32) * 32];
  u16* lB1 = &Bl[(w * 32 + 16) * 32];
  const size_t r16 = (size_t)16 * K;

  f32x4 acc[4][4] = {};

  for (int k0 = 0; k0 < K; k0 += 32) {
    gload_lds16(gA0 + k0, lA0);
    gload_lds16(gA0 + r16 + k0, lA1);
    gload_lds16(gB0 + k0, lB0);
    gload_lds16(gB0 + r16 + k0, lB1);
    __syncthreads();
    bf16x8 af[4], bfr[4];
    #pragma unroll
    for (int m = 0; m < 4; ++m)
      af[m] = *(const bf16x8*)(&Al[(wr * 64 + m * 16 + lr) * 32 + lg * 8]);
    #pragma unroll
    for (int n = 0; n < 4; ++n)
      bfr[n] = *(const bf16x8*)(&Bl[(wc * 64 + n * 16 + lr) * 32 + lg * 8]);
    __builtin_amdgcn_s_setprio(1);
    #pragma unroll
    for (int m = 0; m < 4; ++m) {
      #pragma unroll
      for (int n = 0; n < 4; ++n)
        acc[m][n] = MFMA16(af[m], bfr[n], acc[m][n]);
    }
    __builtin_amdgcn_s_setprio(0);
    __syncthreads();
  }

  // qscale = (1/sqrt(128)) * log2(e): softmax runs in exp2 domain
  const float qscale = 0.12752869468f;
  #pragma unroll
  for (int m = 0; m < 4; ++m) {
    #pragma unroll
    for (int n = 0; n < 4; ++n) {
      const int gm0 = bm + wr * 64 + m * 16 + lg * 4;
      const int gn = bn + wc * 64 + n * 16 + lr;
      if constexpr (MODE == 0) {
        const int b = gm0 >> 11, tq0 = gm0 & (T_ - 1);
        if (gn < 1024) {            // Q, scaled
          int hh = gn >> 7, d = gn & 127;
          #pragma unroll
          for (int r = 0; r < 4; ++r)
            Qb[(((size_t)(b * H_ + hh) * T_ + tq0 + r) << 7) + d] =
                f2bf((acc[m][n][r] + pe[((tq0 + r) << 7) + d]) * qscale);
        } else if (gn < 1152) {     // K (+pe(1,D): +1 on odd d)
          int d = gn - 1024;
          #pragma unroll
          for (int r = 0; r < 4; ++r)
            Kb[((size_t)(gm0 + r) << 7) + d] = f2bf(acc[m][n][r] + (float)(d & 1));
        } else {                    // V^T [b][d][t]
          int d = gn - 1152;
          uint2 pk;
          pk.x = pkbf(acc[m][n][0], acc[m][n][1]);
          pk.y = pkbf(acc[m][n][2], acc[m][n][3]);
          *(uint2*)(VTb + ((size_t)(b * 128 + d) << 11) + tq0) = pk;
        }
      } else {
        #pragma unroll
        for (int r = 0; r < 4; ++r)
          Cout[(size_t)(gm0 + r) * 1024 + gn] = acc[m][n][r];
      }
    }
  }
}

// ---- Flash attention, causal, MQA. R17 macro-structure (KVBLK=64 dbuf,
// paired frags, 1 barrier/tile) with P shrunk to 8KB via two 32-kv
// half-passes (same-wave write->read) -> LDS 72KB -> 2 blocks/CU.
// No setprio (R21). Swizzle keys: K/VT rows 8 units -> lr&7; P rows 4 units -> lr&3.
__global__ __launch_bounds__(512) void attn_kernel(
    const u16* __restrict__ Qb, const u16* __restrict__ Kb,
    const u16* __restrict__ VTg, u16* __restrict__ Ob)
{
  __shared__ u16 Kl[2][64 * 128];    // [buf][kv][d], swizzled content
  __shared__ u16 VTl[2][128 * 64];   // [buf][d][kv], swizzled content
  __shared__ u16 Pl[8 * 16 * 32];    // per-wave P[q][32kv] (half-pass), 8KB
  const int t = threadIdx.x;
  const int l = t & 63, w = t >> 6;       // wave = head
  const int lr = l & 15, lg = l >> 4;
  const int sw = lr & 7;                  // K/VT read-swizzle key (row&7)
  const int sw2 = lr & 3;                 // P swizzle key (4 units/row)
  const int p = blockIdx.x, b = blockIdx.y;
  const int h = w;
  const int q0A = p * 16, q0B = (127 - p) * 16;
  const int ntA = (q0A + 16 + 63) >> 6, ntB = (q0B + 16 + 63) >> 6;

  auto stage = [&](int kt, int s) {
    #pragma unroll
    for (int c = 0; c < 2; ++c) {
      int n = c * 512 + t;
      {
        int row = n >> 4, ul = n & 15;
        int ug = ul ^ (row & 7);
        gload_lds16(Kb + ((size_t)(b * T_ + kt * 64 + row) << 7) + ug * 8,
                    &Kl[s][(size_t)(c * 512 + w * 64) * 8]);
      }
      {
        int row = n >> 3, ul = n & 7;
        int ug = ul ^ (row & 7);
        gload_lds16(VTg + ((size_t)(b * 128 + row) << 11) + kt * 64 + ug * 8,
                    &VTl[s][(size_t)(c * 512 + w * 64) * 8]);
      }
    }
  };

  const u16* qbA = Qb + (((size_t)(b * H_ + h) * T_ + q0A + lr) << 7);
  const u16* qbB = Qb + (((size_t)(b * H_ + h) * T_ + q0B + lr) << 7);
  bf16x8 qfA[4], qfB[4];
  #pragma unroll
  for (int kc = 0; kc < 4; ++kc) {
    qfA[kc] = *(const bf16x8*)(qbA + kc * 32 + lg * 8);
    qfB[kc] = *(const bf16x8*)(qbB + kc * 32 + lg * 8);
  }

  float mA = -3e38f, mB = -3e38f, lA = 0.f, lB = 0.f;
  f32x4 oA[8] = {}, oB[8] = {};
  u16* pw = &Pl[w * 16 * 32];

  auto process = [&](f32x4 (&s)[4], float& m, float& lsum, f32x4 (&o)[8],
                     int q0F, int kt, bool masked, const u16* vtl) {
    float pv[16];
    float pm = -3e38f;
    if (masked) {
      const int qv = q0F + lr;
      #pragma unroll
      for (int kvf = 0; kvf < 4; ++kvf) {
        #pragma unroll
        for (int r = 0; r < 4; ++r) {
          int kv = kt * 64 + kvf * 16 + lg * 4 + r;
          float sv = (kv <= qv) ? s[kvf][r] : -3e38f;
          pv[kvf * 4 + r] = sv;
          pm = fmaxf(pm, sv);
        }
      }
    } else {
      #pragma unroll
      for (int kvf = 0; kvf < 4; ++kvf) {
        #pragma unroll
        for (int r = 0; r < 4; ++r) {
          float sv = s[kvf][r];
          pv[kvf * 4 + r] = sv;
          pm = fmaxf(pm, sv);
        }
      }
    }
    pm = fmaxf(pm, __shfl_xor(pm, 16));
    pm = fmaxf(pm, __shfl_xor(pm, 32));
    float mn;
    if (__all(pm <= m + 11.5f)) {       // defer-max (2^11.5 ~ e^8)
      mn = m;
    } else {
      mn = fmaxf(m, pm);
      float corr = fexp2(m - mn);
      lsum *= corr;
      #pragma unroll
      for (int df = 0; df < 8; ++df) {
        #pragma unroll
        for (int r = 0; r < 4; ++r) o[df][r] *= corr;
      }
      m = mn;
    }
    float ps = 0.f;
    #pragma unroll
    for (int i = 0; i < 16; ++i) {
      pv[i] = fexp2(pv[i] - mn);       // masked -> 2^(-huge) = 0
      ps += pv[i];
    }
    ps += __shfl_xor(ps, 16);
    ps += __shfl_xor(ps, 32);
    lsum += ps;
    // PV in two 32-kv half-passes (same-wave LDS write->read, in order)
    #pragma unroll
    for (int h2 = 0; h2 < 2; ++h2) {
      #pragma unroll
      for (int k2 = 0; k2 < 2; ++k2) {
        int kvf = h2 * 2 + k2;
        uint2 pk;
        pk.x = pkbf(pv[kvf * 4 + 0], pv[kvf * 4 + 1]);
        pk.y = pkbf(pv[kvf * 4 + 2], pv[kvf * 4 + 3]);
        int un = ((2 * k2 + (lg >> 1)) ^ sw2) * 8 + (lg & 1) * 4;
        *(uint2*)(&pw[lr * 32 + un]) = pk;
      }
      bf16x8 pf = *(const bf16x8*)(&pw[lr * 32 + (lg ^ sw2) * 8]);
      #pragma unroll
      for (int df = 0; df < 8; ++df) {
        bf16x8 vf = *(const bf16x8*)(
            &vtl[(df * 16 + lr) * 64 + ((4 * h2 + lg) ^ sw) * 8]);
        o[df] = MFMA16(vf, pf, o[df]);
      }
    }
  };

  // prologue: stage tile 0 into buf 0
  stage(0, 0);
  __syncthreads();

  for (int kt = 0; kt < ntB; ++kt) {
    const int cur = kt & 1;
    if (kt + 1 < ntB) stage(kt + 1, cur ^ 1);   // async, register-free

    const bool actA = kt < ntA;   // block-uniform
    f32x4 sA[4] = {}, sB[4] = {};
    #pragma unroll
    for (int kvf = 0; kvf < 4; ++kvf) {
      bf16x8 kf[4];
      #pragma unroll
      for (int kc = 0; kc < 4; ++kc)
        kf[kc] = *(const bf16x8*)(&Kl[cur][((kvf * 16 + lr) << 7) + ((4 * kc + lg) ^ sw) * 8]);
      #pragma unroll
      for (int kc = 0; kc < 4; ++kc)
        sB[kvf] = MFMA16(kf[kc], qfB[kc], sB[kvf]);
      if (actA) {
        #pragma unroll
        for (int kc = 0; kc < 4; ++kc)
          sA[kvf] = MFMA16(kf[kc], qfA[kc], sA[kvf]);
      }
    }
    process(sB, mB, lB, oB, q0B, kt, kt * 64 + 63 > q0B, &VTl[cur][0]);
    if (actA) process(sA, mA, lA, oA, q0A, kt, kt * 64 + 63 > q0A, &VTl[cur][0]);
    __syncthreads();   // kt's readers done; kt+1's stage loads drained
  }

  float rA = 1.0f / lA, rB = 1.0f / lB;
  #pragma unroll
  for (int df = 0; df < 8; ++df) {
    uint2 pk;
    pk.x = pkbf(oB[df][0] * rB, oB[df][1] * rB);
    pk.y = pkbf(oB[df][2] * rB, oB[df][3] * rB);
    *(uint2*)(Ob + ((size_t)(b * T_ + q0B + lr) << 10) + h * 128 + df * 16 + lg * 4) = pk;
    pk.x = pkbf(oA[df][0] * rA, oA[df][1] * rA);
    pk.y = pkbf(oA[df][2] * rA, oA[df][3] * rA);
    *(uint2*)(Ob + ((size_t)(b * T_ + q0A + lr) << 10) + h * 128 + df * 16 + lg * 4) = pk;
  }
}

extern "C" void kernel_launch(void* const* d_in, const int* in_sizes, int n_in,
                              void* d_out, int out_size, void* d_ws, size_t ws_size,
                              hipStream_t stream) {
  const float* x  = (const float*)d_in[0];
  const float* Wq = (const float*)d_in[1];
  const float* Wk = (const float*)d_in[2];
  const float* Wv = (const float*)d_in[3];
  const float* Wo = (const float*)d_in[4];

  char* ws = (char*)d_ws;
  size_t off = 0;
  auto alloc = [&](size_t bytes) {
    char* p = ws + off;
    off += (bytes + 255) & ~(size_t)255;
    return p;
  };
  u16*   xbf  = (u16*)  alloc(8388608ull * 2);   // x bf16 [8192][1024]
  u16*   Wcat = (u16*)  alloc(1310720ull * 2);   // [Wq;Wk;Wv] bf16 [1280][1024]
  u16*   Wobf = (u16*)  alloc(1048576ull * 2);   // Wo bf16 [1024][1024]
  float* pe   = (float*)alloc(262144ull * 4);    // PE table [2048][128] fp32
  u16*   Qbuf = (u16*)  alloc(8388608ull * 2);   // Q bf16 [B][H][T][D] (pre-scaled)
  u16*   Kbuf = (u16*)  alloc(1048576ull * 2);   // K bf16 [B*T][D]
  u16*   VTbuf= (u16*)  alloc(1048576ull * 2);   // V^T bf16 [B][D][T]
  u16*   Abuf = (u16*)  alloc(8388608ull * 2);   // attn out bf16 [B*T][H*D]

  prep_kernel<<<11008, 256, 0, stream>>>(x, Wq, Wk, Wv, Wo, xbf, Wcat, Wobf, pe);

  gemm_nt<0><<<dim3(64, 10), 256, 0, stream>>>(xbf, Wcat, Qbuf, Kbuf, VTbuf, pe, nullptr, 1024);
  attn_kernel<<<dim3(64, 4), 512, 0, stream>>>(Qbuf, Kbuf, VTbuf, Abuf);
  gemm_nt<1><<<dim3(64, 8), 256, 0, stream>>>(Abuf, Wobf, nullptr, nullptr, nullptr, nullptr,
                                              (float*)d_out, 1024);
}

// Round 23
// 131.911 us; speedup vs baseline: 1.1188x; 1.1188x over previous
//
#include <hip/hip_runtime.h>
#include <hip/hip_bf16.h>
#include <cstdint>
#include <cstddef>

#define B_ 4
#define T_ 2048
#define E_ 1024
#define H_ 8
#define D_ 128

typedef unsigned short u16;
typedef __bf16 bf16x8 __attribute__((ext_vector_type(8)));
typedef float f32x4 __attribute__((ext_vector_type(4)));

#define MFMA16(a, b, c) __builtin_amdgcn_mfma_f32_16x16x32_bf16((a), (b), (c), 0, 0, 0)

#if defined(__has_builtin)
#if __has_builtin(__builtin_amdgcn_global_load_lds)
#define HAVE_GLL 1
#endif
#if __has_builtin(__builtin_amdgcn_exp2f)
#define HAVE_EXP2 1
#endif
#endif

__device__ __forceinline__ void gload_lds16(const u16* g, u16* l) {
#ifdef HAVE_GLL
  __builtin_amdgcn_global_load_lds(
      (const __attribute__((address_space(1))) void*)g,
      (__attribute__((address_space(3))) void*)l, 16, 0, 0);
#else
  int lane = threadIdx.x & 63;
  *(uint4*)(l + lane * 8) = *(const uint4*)(g);
#endif
}

// 2^x via raw v_exp_f32
__device__ __forceinline__ float fexp2(float x) {
#ifdef HAVE_EXP2
  return __builtin_amdgcn_exp2f(x);
#else
  return __expf(x * 0.69314718056f);
#endif
}

__device__ __forceinline__ u16 f2bf(float f) {
  union { float f; uint32_t u; } a; a.f = f;
  uint32_t u = a.u;
  uint32_t r = (u + 0x7fffu + ((u >> 16) & 1u)) >> 16;  // RNE
  return (u16)r;
}

__device__ __forceinline__ uint32_t pkbf(float lo, float hi) {
  uint32_t r;
  asm volatile("v_cvt_pk_bf16_f32 %0, %1, %2" : "=v"(r) : "v"(lo), "v"(hi));
  return r;
}

__device__ __forceinline__ void cvt4(const float* __restrict__ s, u16* __restrict__ d, int i4) {
  float4 v = *(const float4*)(s + (size_t)i4 * 4);
  uint2 o;
  o.x = (uint32_t)f2bf(v.x) | ((uint32_t)f2bf(v.y) << 16);
  o.y = (uint32_t)f2bf(v.z) | ((uint32_t)f2bf(v.w) << 16);
  *(uint2*)(d + (size_t)i4 * 4) = o;
}

// ---- fused prep: all fp32->bf16 conversions + PE table, one launch ----
__global__ __launch_bounds__(256) void prep_kernel(
    const float* __restrict__ x,  const float* __restrict__ Wq,
    const float* __restrict__ Wk, const float* __restrict__ Wv,
    const float* __restrict__ Wo,
    u16* __restrict__ xbf, u16* __restrict__ Wcat, u16* __restrict__ Wobf,
    float* __restrict__ pe)
{
  int id = blockIdx.x * 256 + threadIdx.x;
  if (id < 2097152) { cvt4(x, xbf, id); return; }
  id -= 2097152;
  if (id < 262144) { cvt4(Wq, Wcat, id); return; }
  id -= 262144;
  if (id < 32768) { cvt4(Wk, Wcat + 1048576, id); return; }
  id -= 32768;
  if (id < 32768) { cvt4(Wv, Wcat + 1179648, id); return; }
  id -= 32768;
  if (id < 262144) { cvt4(Wo, Wobf, id); return; }
  id -= 262144;
  // PE: id in [0, 131072)
  int t = id >> 6, i = id & 63;
  float f = expf(-logf(10000.0f) * (float)i / 64.0f);
  float ang = (float)t * f;
  pe[t * 128 + 2 * i]     = sinf(ang);
  pe[t * 128 + 2 * i + 1] = cosf(ang);
}

// ---- NT GEMM, m97 structure + register-free double-buffer:
// stage(k+1) async at iteration top, compute(k), ONE barrier per K-step
// (drain lands after ~2000cy of MFMA instead of right after issue).
template<int MODE>
__global__ __launch_bounds__(256) void gemm_nt(
    const u16* __restrict__ A, const u16* __restrict__ Bm,
    u16* __restrict__ Qb, u16* __restrict__ Kb, u16* __restrict__ VTb,
    const float* __restrict__ pe, float* __restrict__ Cout, int K)
{
  __shared__ u16 Al[2][128 * 32];
  __shared__ u16 Bl[2][128 * 32];
  const int t = threadIdx.x;
  const int l = t & 63, w = t >> 6;
  const int wr = w >> 1, wc = w & 1;
  const int bm = blockIdx.x * 128, bn = blockIdx.y * 128;
  const int lr = l & 15, lg = l >> 4;

  const int srow = w * 32 + (l >> 2);
  const int scol = (l & 3) * 8;
  const u16* gA0 = A + (size_t)(bm + srow) * K + scol;
  const u16* gB0 = Bm + (size_t)(bn + srow) * K + scol;
  const size_t r16 = (size_t)16 * K;

  auto stage = [&](int k0, int s) {
    gload_lds16(gA0 + k0, &Al[s][(w * 32) * 32]);
    gload_lds16(gA0 + r16 + k0, &Al[s][(w * 32 + 16) * 32]);
    gload_lds16(gB0 + k0, &Bl[s][(w * 32) * 32]);
    gload_lds16(gB0 + r16 + k0, &Bl[s][(w * 32 + 16) * 32]);
  };

  f32x4 acc[4][4] = {};
  const int nIt = K >> 5;

  stage(0, 0);
  __syncthreads();

  for (int i = 0; i < nIt; ++i) {
    const int cur = i & 1;
    if (i + 1 < nIt) stage((i + 1) << 5, cur ^ 1);   // async, register-free
    bf16x8 af[4], bfr[4];
    #pragma unroll
    for (int m = 0; m < 4; ++m)
      af[m] = *(const bf16x8*)(&Al[cur][(wr * 64 + m * 16 + lr) * 32 + lg * 8]);
    #pragma unroll
    for (int n = 0; n < 4; ++n)
      bfr[n] = *(const bf16x8*)(&Bl[cur][(wc * 64 + n * 16 + lr) * 32 + lg * 8]);
    __builtin_amdgcn_s_setprio(1);
    #pragma unroll
    for (int m = 0; m < 4; ++m) {
      #pragma unroll
      for (int n = 0; n < 4; ++n)
        acc[m][n] = MFMA16(af[m], bfr[n], acc[m][n]);
    }
    __builtin_amdgcn_s_setprio(0);
    __syncthreads();   // readers of buf[cur] done; stage(i+1) drained
  }

  // qscale = (1/sqrt(128)) * log2(e): softmax runs in exp2 domain
  const float qscale = 0.12752869468f;
  #pragma unroll
  for (int m = 0; m < 4; ++m) {
    #pragma unroll
    for (int n = 0; n < 4; ++n) {
      const int gm0 = bm + wr * 64 + m * 16 + lg * 4;
      const int gn = bn + wc * 64 + n * 16 + lr;
      if constexpr (MODE == 0) {
        const int b = gm0 >> 11, tq0 = gm0 & (T_ - 1);
        if (gn < 1024) {            // Q, scaled
          int hh = gn >> 7, d = gn & 127;
          #pragma unroll
          for (int r = 0; r < 4; ++r)
            Qb[(((size_t)(b * H_ + hh) * T_ + tq0 + r) << 7) + d] =
                f2bf((acc[m][n][r] + pe[((tq0 + r) << 7) + d]) * qscale);
        } else if (gn < 1152) {     // K (+pe(1,D): +1 on odd d)
          int d = gn - 1024;
          #pragma unroll
          for (int r = 0; r < 4; ++r)
            Kb[((size_t)(gm0 + r) << 7) + d] = f2bf(acc[m][n][r] + (float)(d & 1));
        } else {                    // V^T [b][d][t]
          int d = gn - 1152;
          uint2 pk;
          pk.x = pkbf(acc[m][n][0], acc[m][n][1]);
          pk.y = pkbf(acc[m][n][2], acc[m][n][3]);
          *(uint2*)(VTb + ((size_t)(b * 128 + d) << 11) + tq0) = pk;
        }
      } else {
        #pragma unroll
        for (int r = 0; r < 4; ++r)
          Cout[(size_t)(gm0 + r) * 1024 + gn] = acc[m][n][r];
      }
    }
  }
}

// ---- Flash attention, causal, MQA. R21-exact (best measured: 66.4us):
// dbuf, paired frags, 1 barrier/tile, KVBLK=128, P 16KB via two 64-kv
// half-passes, no setprio.
__global__ __launch_bounds__(512) void attn_kernel(
    const u16* __restrict__ Qb, const u16* __restrict__ Kb,
    const u16* __restrict__ VTg, u16* __restrict__ Ob)
{
  __shared__ u16 Kl[2][128 * 128];   // [buf][kv][d], swizzled content
  __shared__ u16 VTl[2][128 * 128];  // [buf][d][kv], swizzled content
  __shared__ u16 Pl[8 * 16 * 64];    // per-wave P[q][64kv] (half-pass)
  const int t = threadIdx.x;
  const int l = t & 63, w = t >> 6;       // wave = head
  const int lr = l & 15, lg = l >> 4;
  const int sw = lr & 7;                  // read-swizzle key (row&7)
  const int p = blockIdx.x, b = blockIdx.y;
  const int h = w;
  const int q0A = p * 16, q0B = (127 - p) * 16;
  const int ntA = (q0A + 16 + 127) >> 7, ntB = (q0B + 16 + 127) >> 7;

  auto stage = [&](int kt, int s) {
    #pragma unroll
    for (int c = 0; c < 4; ++c) {
      int n = c * 512 + t;
      int row = n >> 4, ul = n & 15;
      int ug = ul ^ (row & 7);
      gload_lds16(Kb + ((size_t)(b * T_ + kt * 128 + row) << 7) + ug * 8,
                  &Kl[s][(size_t)(c * 512 + w * 64) * 8]);
      gload_lds16(VTg + ((size_t)(b * 128 + row) << 11) + kt * 128 + ug * 8,
                  &VTl[s][(size_t)(c * 512 + w * 64) * 8]);
    }
  };

  const u16* qbA = Qb + (((size_t)(b * H_ + h) * T_ + q0A + lr) << 7);
  const u16* qbB = Qb + (((size_t)(b * H_ + h) * T_ + q0B + lr) << 7);
  bf16x8 qfA[4], qfB[4];
  #pragma unroll
  for (int kc = 0; kc < 4; ++kc) {
    qfA[kc] = *(const bf16x8*)(qbA + kc * 32 + lg * 8);
    qfB[kc] = *(const bf16x8*)(qbB + kc * 32 + lg * 8);
  }

  float mA = -3e38f, mB = -3e38f, lA = 0.f, lB = 0.f;
  f32x4 oA[8] = {}, oB[8] = {};
  u16* pw = &Pl[w * 16 * 64];

  auto process = [&](f32x4 (&s)[8], float& m, float& lsum, f32x4 (&o)[8],
                     int q0F, int kt, bool masked, const u16* vtl) {
    float pv[32];
    float pm = -3e38f;
    if (masked) {
      const int qv = q0F + lr;
      #pragma unroll
      for (int kvf = 0; kvf < 8; ++kvf) {
        #pragma unroll
        for (int r = 0; r < 4; ++r) {
          int kv = kt * 128 + kvf * 16 + lg * 4 + r;
          float sv = (kv <= qv) ? s[kvf][r] : -3e38f;
          pv[kvf * 4 + r] = sv;
          pm = fmaxf(pm, sv);
        }
      }
    } else {
      #pragma unroll
      for (int kvf = 0; kvf < 8; ++kvf) {
        #pragma unroll
        for (int r = 0; r < 4; ++r) {
          float sv = s[kvf][r];
          pv[kvf * 4 + r] = sv;
          pm = fmaxf(pm, sv);
        }
      }
    }
    pm = fmaxf(pm, __shfl_xor(pm, 16));
    pm = fmaxf(pm, __shfl_xor(pm, 32));
    float mn;
    if (__all(pm <= m + 11.5f)) {       // defer-max (2^11.5 ~ e^8)
      mn = m;
    } else {
      mn = fmaxf(m, pm);
      float corr = fexp2(m - mn);
      lsum *= corr;
      #pragma unroll
      for (int df = 0; df < 8; ++df) {
        #pragma unroll
        for (int r = 0; r < 4; ++r) o[df][r] *= corr;
      }
      m = mn;
    }
    float ps = 0.f;
    #pragma unroll
    for (int i = 0; i < 32; ++i) {
      pv[i] = fexp2(pv[i] - mn);       // masked -> 2^(-huge) = 0
      ps += pv[i];
    }
    ps += __shfl_xor(ps, 16);
    ps += __shfl_xor(ps, 32);
    lsum += ps;
    // PV in two 64-kv half-passes (same-wave LDS write->read, in order)
    #pragma unroll
    for (int h2 = 0; h2 < 2; ++h2) {
      #pragma unroll
      for (int k4 = 0; k4 < 4; ++k4) {
        int kvf = h2 * 4 + k4;
        uint2 pk;
        pk.x = pkbf(pv[kvf * 4 + 0], pv[kvf * 4 + 1]);
        pk.y = pkbf(pv[kvf * 4 + 2], pv[kvf * 4 + 3]);
        int un = ((2 * k4 + (lg >> 1)) ^ sw) * 8 + (lg & 1) * 4;
        *(uint2*)(&pw[lr * 64 + un]) = pk;
      }
      #pragma unroll
      for (int kc = 0; kc < 2; ++kc) {
        int kcg = h2 * 2 + kc;   // global 32-kv chunk
        bf16x8 pf = *(const bf16x8*)(&pw[lr * 64 + ((4 * kc + lg) ^ sw) * 8]);
        #pragma unroll
        for (int df = 0; df < 8; ++df) {
          bf16x8 vf = *(const bf16x8*)(
              &vtl[((df * 16 + lr) << 7) + ((4 * kcg + lg) ^ sw) * 8]);
          o[df] = MFMA16(vf, pf, o[df]);
        }
      }
    }
  };

  // prologue: stage tile 0 into buf 0
  stage(0, 0);
  __syncthreads();

  for (int kt = 0; kt < ntB; ++kt) {
    const int cur = kt & 1;
    if (kt + 1 < ntB) stage(kt + 1, cur ^ 1);   // async, register-free

    const bool actA = kt < ntA;   // block-uniform
    f32x4 sA[8] = {}, sB[8] = {};
    #pragma unroll
    for (int kvf = 0; kvf < 8; ++kvf) {
      bf16x8 kf[4];
      #pragma unroll
      for (int kc = 0; kc < 4; ++kc)
        kf[kc] = *(const bf16x8*)(
            &Kl[cur][((kvf * 16 + lr) << 7) + ((4 * kc + lg) ^ sw) * 8]);
      #pragma unroll
      for (int kc = 0; kc < 4; ++kc)
        sB[kvf] = MFMA16(kf[kc], qfB[kc], sB[kvf]);
      if (actA) {
        #pragma unroll
        for (int kc = 0; kc < 4; ++kc)
          sA[kvf] = MFMA16(kf[kc], qfA[kc], sA[kvf]);
      }
    }
    process(sB, mB, lB, oB, q0B, kt, kt * 128 + 127 > q0B, &VTl[cur][0]);
    if (actA) process(sA, mA, lA, oA, q0A, kt, kt * 128 + 127 > q0A, &VTl[cur][0]);
    __syncthreads();   // kt's readers done; kt+1's stage loads drained
  }

  float rA = 1.0f / lA, rB = 1.0f / lB;
  #pragma unroll
  for (int df = 0; df < 8; ++df) {
    uint2 pk;
    pk.x = pkbf(oB[df][0] * rB, oB[df][1] * rB);
    pk.y = pkbf(oB[df][2] * rB, oB[df][3] * rB);
    *(uint2*)(Ob + ((size_t)(b * T_ + q0B + lr) << 10) + h * 128 + df * 16 + lg * 4) = pk;
    pk.x = pkbf(oA[df][0] * rA, oA[df][1] * rA);
    pk.y = pkbf(oA[df][2] * rA, oA[df][3] * rA);
    *(uint2*)(Ob + ((size_t)(b * T_ + q0A + lr) << 10) + h * 128 + df * 16 + lg * 4) = pk;
  }
}

extern "C" void kernel_launch(void* const* d_in, const int* in_sizes, int n_in,
                              void* d_out, int out_size, void* d_ws, size_t ws_size,
                              hipStream_t stream) {
  const float* x  = (const float*)d_in[0];
  const float* Wq = (const float*)d_in[1];
  const float* Wk = (const float*)d_in[2];
  const float* Wv = (const float*)d_in[3];
  const float* Wo = (const float*)d_in[4];

  char* ws = (char*)d_ws;
  size_t off = 0;
  auto alloc = [&](size_t bytes) {
    char* p = ws + off;
    off += (bytes + 255) & ~(size_t)255;
    return p;
  };
  u16*   xbf  = (u16*)  alloc(8388608ull * 2);   // x bf16 [8192][1024]
  u16*   Wcat = (u16*)  alloc(1310720ull * 2);   // [Wq;Wk;Wv] bf16 [1280][1024]
  u16*   Wobf = (u16*)  alloc(1048576ull * 2);   // Wo bf16 [1024][1024]
  float* pe   = (float*)alloc(262144ull * 4);    // PE table [2048][128] fp32
  u16*   Qbuf = (u16*)  alloc(8388608ull * 2);   // Q bf16 [B][H][T][D] (pre-scaled)
  u16*   Kbuf = (u16*)  alloc(1048576ull * 2);   // K bf16 [B*T][D]
  u16*   VTbuf= (u16*)  alloc(1048576ull * 2);   // V^T bf16 [B][D][T]
  u16*   Abuf = (u16*)  alloc(8388608ull * 2);   // attn out bf16 [B*T][H*D]

  prep_kernel<<<11008, 256, 0, stream>>>(x, Wq, Wk, Wv, Wo, xbf, Wcat, Wobf, pe);

  gemm_nt<0><<<dim3(64, 10), 256, 0, stream>>>(xbf, Wcat, Qbuf, Kbuf, VTbuf, pe, nullptr, 1024);
  attn_kernel<<<dim3(64, 4), 512, 0, stream>>>(Qbuf, Kbuf, VTbuf, Abuf);
  gemm_nt<1><<<dim3(64, 8), 256, 0, stream>>>(Abuf, Wobf, nullptr, nullptr, nullptr, nullptr,
                                              (float*)d_out, 1024);
}